// Round 1
// baseline (106.359 us; speedup 1.0000x reference)
//
#include <hip/hip_runtime.h>
#include <float.h>

// Problem constants (B=8, N=8192, D=3)
#define NB 8
#define NPTS 8192
#define BLK 256
#define APT 8                       // adv points per thread
#define OSPLIT 16                   // ori-dimension split
#define OCHUNK (NPTS / OSPLIT)      // 512 ori points per block (8 KB LDS as float4)
#define ADV_PER_BLOCK (BLK * APT)   // 2048
#define ADV_CHUNKS (NPTS / ADV_PER_BLOCK) // 4
#define TOTAL (NB * NPTS)           // 65536 adv points overall

// Monotone float -> uint mapping so unsigned atomicMin orders like float min
// (distances can be ~-1e-6 from fp cancellation, so handle negatives).
__device__ __forceinline__ unsigned int enc_f32(float f) {
    unsigned int b = __float_as_uint(f);
    return (b & 0x80000000u) ? ~b : (b | 0x80000000u);
}
__device__ __forceinline__ float dec_f32(unsigned int e) {
    unsigned int b = (e & 0x80000000u) ? (e & 0x7fffffffu) : ~e;
    return __uint_as_float(b);
}

__global__ __launch_bounds__(BLK) void init_slots(unsigned int* __restrict__ slots) {
    int g = blockIdx.x * BLK + threadIdx.x;
    if (g < TOTAL) slots[g] = 0xFFFFFFFFu;   // encodes +inf (max key)
}

// Each block: one (batch, adv-chunk of 2048, ori-split of 512) tile.
// Thread owns 8 adv points in registers; wave iterates ori points via
// same-address LDS broadcast (float4 = x,y,z,0.5*|o|^2).
__global__ __launch_bounds__(BLK) void chamfer_main(const float* __restrict__ adv,
                                                    const float* __restrict__ ori,
                                                    unsigned int* __restrict__ slots) {
    const int bx = blockIdx.x;
    const int b = bx >> 6;               // 64 blocks per batch
    const int rem = bx & 63;
    const int advChunk = rem & (ADV_CHUNKS - 1);
    const int split = rem >> 2;

    __shared__ float4 opts[OCHUNK];

    // Stage this block's ori chunk into LDS, precomputing 0.5*ro.
    const float* orib = ori + ((size_t)b * NPTS + (size_t)split * OCHUNK) * 3;
    for (int p = threadIdx.x; p < OCHUNK; p += BLK) {
        float x = orib[3 * p + 0];
        float y = orib[3 * p + 1];
        float z = orib[3 * p + 2];
        opts[p] = make_float4(x, y, z, 0.5f * (x * x + y * y + z * z));
    }

    // Load my 8 adv points (negated coords + squared norm).
    const float* advb = adv + (size_t)b * NPTS * 3;
    const int advBase = advChunk * ADV_PER_BLOCK;
    float nax[APT], nay[APT], naz[APT], ra[APT], um[APT];
#pragma unroll
    for (int i = 0; i < APT; i++) {
        int j = advBase + threadIdx.x + i * BLK;
        float x = advb[3 * j + 0];
        float y = advb[3 * j + 1];
        float z = advb[3 * j + 2];
        nax[i] = -x; nay[i] = -y; naz[i] = -z;
        ra[i] = x * x + y * y + z * z;
        um[i] = FLT_MAX;
    }
    __syncthreads();

    // Main loop: u = 0.5*ro - dot(a,o); min over u (ra const per adv pt).
#pragma unroll 2
    for (int k = 0; k < OCHUNK; k++) {
        float4 o = opts[k];
#pragma unroll
        for (int i = 0; i < APT; i++) {
            float u = fmaf(nax[i], o.x, fmaf(nay[i], o.y, fmaf(naz[i], o.z, o.w)));
            um[i] = fminf(um[i], u);
        }
    }

    // d = ra + 2*u_min; combine partial mins across ori-splits.
#pragma unroll
    for (int i = 0; i < APT; i++) {
        float d = fmaf(2.0f, um[i], ra[i]);
        int j = b * NPTS + advBase + threadIdx.x + i * BLK;
        atomicMin(&slots[j], enc_f32(d));
    }
}

// Per-block weighted partial sums of the 65536 mins.
__global__ __launch_bounds__(BLK) void reduce1(const unsigned int* __restrict__ slots,
                                               const float* __restrict__ w,
                                               float* __restrict__ bsums) {
    __shared__ float red[BLK];
    int g = blockIdx.x * BLK + threadIdx.x;
    float d = dec_f32(slots[g]);
    float v = d * w[g >> 13];          // 8192 = 2^13 points per batch
    red[threadIdx.x] = v;
    __syncthreads();
    for (int s = BLK / 2; s > 0; s >>= 1) {
        if (threadIdx.x < s) red[threadIdx.x] += red[threadIdx.x + s];
        __syncthreads();
    }
    if (threadIdx.x == 0) bsums[blockIdx.x] = red[0];
}

__global__ __launch_bounds__(BLK) void reduce2(const float* __restrict__ bsums,
                                               float* __restrict__ out) {
    __shared__ float red[BLK];
    red[threadIdx.x] = bsums[threadIdx.x];
    __syncthreads();
    for (int s = BLK / 2; s > 0; s >>= 1) {
        if (threadIdx.x < s) red[threadIdx.x] += red[threadIdx.x + s];
        __syncthreads();
    }
    if (threadIdx.x == 0) out[0] = red[0] * (1.0f / (float)TOTAL);
}

extern "C" void kernel_launch(void* const* d_in, const int* in_sizes, int n_in,
                              void* d_out, int out_size, void* d_ws, size_t ws_size,
                              hipStream_t stream) {
    const float* adv = (const float*)d_in[0];   // adv_pc [8,8192,3] f32
    const float* ori = (const float*)d_in[1];   // ori_pc [8,8192,3] f32
    const float* w   = (const float*)d_in[2];   // weights [8] f32
    float* out = (float*)d_out;

    unsigned int* slots = (unsigned int*)d_ws;                         // 256 KB
    float* bsums = (float*)((char*)d_ws + (size_t)TOTAL * sizeof(unsigned int)); // 1 KB

    hipLaunchKernelGGL(init_slots, dim3(TOTAL / BLK), dim3(BLK), 0, stream, slots);
    hipLaunchKernelGGL(chamfer_main, dim3(NB * OSPLIT * ADV_CHUNKS), dim3(BLK), 0, stream,
                       adv, ori, slots);
    hipLaunchKernelGGL(reduce1, dim3(TOTAL / BLK), dim3(BLK), 0, stream, slots, w, bsums);
    hipLaunchKernelGGL(reduce2, dim3(1), dim3(BLK), 0, stream, bsums, out);
}